// Round 3
// baseline (181.747 us; speedup 1.0000x reference)
//
#include <hip/hip_runtime.h>

#define NCC 20
#define AA  5
#define MM  50
#define HWC 1024      // 32x32 cells per batch
#define NB  256       // batches == blocks

// One block = one batch (1024 threads = 1024 cells, 16 waves).
// Target build: scatter into LDS SoA once per block (last-valid-object wins
// for vals via "am I last for my cell" check over <=50 objects; classes OR'd
// with LDS atomicOr), then each cell-thread does ONE conflict-free LDS read
// instead of a 50-iteration scan (was ~300 VALU instr/thread).
// Global reads: conf plane (ch20) x5 anchors for all cells; obj cells (~2.5%)
// additionally read ch21-24 x5 + 20 cls logits of best anchor. ~25 MB total.
__global__ __launch_bounds__(1024) void yolo_loss(
    const float* __restrict__ out,        // [B, 125, 32, 32]
    const float* __restrict__ gt_boxes,   // [B, 50, 4]
    const float* __restrict__ anchor,     // [5, 2]
    const int*   __restrict__ gt_classes, // [B, 50]
    const int*   __restrict__ num_box,    // [B]
    float4*      __restrict__ partials)   // [NB]: (box, conf, noobj, cls)
{
    __shared__ float s_txo[HWC], s_tyo[HWC], s_ttw[HWC], s_tth[HWC];
    __shared__ int   s_tm[HWC];           // class bitmask; 0 => no object
    __shared__ int   s_cell[MM];
    __shared__ float s_anc[2*AA];
    __shared__ int   s_nb;
    __shared__ float s_red[16][4];

    const int tid = threadIdx.x;          // == cell index in batch
    const int b   = blockIdx.x;

    s_tm[tid] = 0;
    if (tid == 0) s_nb = num_box[b];
    if (tid < 2*AA) s_anc[tid] = anchor[tid];

    float oxo = 0.f, oyo = 0.f, otw = 0.f, oth = 0.f;
    int mycell = 0, mycls = 0;
    if (tid < MM) {
        float4 g = ((const float4*)gt_boxes)[b*MM + tid];
        float x = g.x * 32.f;
        float y = g.y * 32.f;
        int gx = (int)floorf(x);
        int gy = (int)floorf(y);
        mycell = gy*32 + gx;
        s_cell[tid] = mycell;
        oxo = x - (float)gx;
        oyo = y - (float)gy;
        otw = g.z * 32.f;
        oth = g.w * 32.f;
        mycls = gt_classes[b*MM + tid];
    }
    __syncthreads();

    int nb = s_nb; if (nb > MM) nb = MM;
    if (tid < nb) {
        // last valid object targeting my cell wins the val channels
        bool winner = true;
        for (int m = tid + 1; m < nb; ++m)
            winner = winner && (s_cell[m] != mycell);
        if (winner) {
            s_txo[mycell] = oxo;
            s_tyo[mycell] = oyo;
            s_ttw[mycell] = otw;
            s_tth[mycell] = oth;
        }
        atomicOr(&s_tm[mycell], 1 << mycls);   // all valid objects' classes
    }
    __syncthreads();

    const float* cellp = out + (size_t)b * (AA*25) * HWC + tid;

    // conf channel, all 5 anchors -- only global read for ~97% of cells
    float pc[AA];
    float noobj_l = 0.f;
    #pragma unroll
    for (int a = 0; a < AA; ++a) {
        float cl = cellp[(a*25 + NCC) * HWC];
        float s  = 1.f / (1.f + __expf(-cl));
        pc[a] = s;
        noobj_l += s * s;
    }

    float box_l = 0.f, conf_l = 0.f, cls_l = 0.f;
    int clsmask = s_tm[tid];

    if (clsmask != 0) {                   // obj cell (~2.5%)
        float xo = s_txo[tid], yo = s_tyo[tid];
        float tw = s_ttw[tid], th = s_tth[tid];
        const float fgx = (float)(tid & 31);
        const float fgy = (float)(tid >> 5);
        const float tbx = fgx + xo;
        const float tby = fgy + yo;

        float best_iou = -1.f;
        int   best = 0;
        float bpx = 0.f, bpy = 0.f, bpw = 0.f, bph = 0.f;
        #pragma unroll
        for (int a = 0; a < AA; ++a) {
            float t21 = cellp[(a*25 + NCC+1) * HWC];
            float t22 = cellp[(a*25 + NCC+2) * HWC];
            float t23 = cellp[(a*25 + NCC+3) * HWC];
            float t24 = cellp[(a*25 + NCC+4) * HWC];
            float px = fgx + 1.f / (1.f + __expf(-t21));
            float py = fgy + 1.f / (1.f + __expf(-t22));
            float pw = __expf(t23) * s_anc[2*a];
            float ph = __expf(t24) * s_anc[2*a+1];
            float iw = fmaxf(fminf(px + pw*0.5f, tbx + tw*0.5f)
                           - fmaxf(px - pw*0.5f, tbx - tw*0.5f), 0.f);
            float ih = fmaxf(fminf(py + ph*0.5f, tby + th*0.5f)
                           - fmaxf(py - ph*0.5f, tby - th*0.5f), 0.f);
            float inter = iw * ih;
            float uni   = pw*ph + tw*th - inter;
            float iou   = inter / fmaxf(uni, 1e-10f);
            if (iou > best_iou) {         // strict > == argmax first-occurrence
                best_iou = iou; best = a;
                bpx = px; bpy = py; bpw = pw; bph = ph;
            }
        }

        float dx = bpx - tbx;
        float dy = bpy - tby;
        float dw = sqrtf(bpw) - sqrtf(tw);
        float dh = sqrtf(bph) - sqrtf(th);
        box_l = dx*dx + dy*dy + dw*dw + dh*dh;

        float cd = pc[best] - 1.f;
        conf_l = cd * cd;
        noobj_l -= pc[best] * pc[best];

        int cls_t = __ffs(clsmask) - 1;   // argmax of multi-hot = lowest bit
        float mx = -1e30f, ssum = 0.f, lt = 0.f;
        #pragma unroll
        for (int i = 0; i < NCC; ++i) {
            float l = cellp[(best*25 + i) * HWC];
            if (i == cls_t) lt = l;
            float nm = fmaxf(mx, l);
            ssum = ssum * __expf(mx - nm) + __expf(l - nm);
            mx = nm;
        }
        cls_l = mx + __logf(ssum) - lt;
    }

    // block reduction: 16 waves -> s_red, thread 0 assembles float4
    float v[4] = { box_l  * (5.0f/256.0f),
                   conf_l * (1.0f/256.0f),
                   noobj_l* (0.5f/256.0f),
                   cls_l  * (1.0f/256.0f) };
    const int lane = tid & 63;
    const int wid  = tid >> 6;
    #pragma unroll
    for (int k = 0; k < 4; ++k) {
        float x = v[k];
        #pragma unroll
        for (int off = 32; off > 0; off >>= 1)
            x += __shfl_down(x, off, 64);
        if (lane == 0) s_red[wid][k] = x;
    }
    __syncthreads();
    if (tid == 0) {
        float4 p;
        float s0=0.f, s1=0.f, s2=0.f, s3=0.f;
        #pragma unroll
        for (int w = 0; w < 16; ++w) {
            s0 += s_red[w][0]; s1 += s_red[w][1];
            s2 += s_red[w][2]; s3 += s_red[w][3];
        }
        p.x = s0; p.y = s1; p.z = s2; p.w = s3;
        partials[b] = p;
    }
}

// Single block: reduce NB float4 partials -> 4 scalars, overwrite d_out.
__global__ __launch_bounds__(256) void reduce_partials(
    const float4* __restrict__ partials, float* __restrict__ loss)
{
    __shared__ float s_red[4][4];
    const int tid = threadIdx.x;

    float4 p = partials[tid];
    float v[4] = { p.x, p.y, p.z, p.w };

    const int lane = tid & 63;
    const int wid  = tid >> 6;
    #pragma unroll
    for (int k = 0; k < 4; ++k) {
        float x = v[k];
        #pragma unroll
        for (int off = 32; off > 0; off >>= 1)
            x += __shfl_down(x, off, 64);
        if (lane == 0) s_red[wid][k] = x;
    }
    __syncthreads();
    if (tid < 4)
        loss[tid] = s_red[0][tid] + s_red[1][tid] + s_red[2][tid] + s_red[3][tid];
}

extern "C" void kernel_launch(void* const* d_in, const int* in_sizes, int n_in,
                              void* d_out, int out_size, void* d_ws, size_t ws_size,
                              hipStream_t stream) {
    const float* out_t      = (const float*)d_in[0];
    const float* gt_boxes   = (const float*)d_in[1];
    const float* anchor     = (const float*)d_in[2];
    const int*   gt_classes = (const int*)d_in[3];
    const int*   num_box    = (const int*)d_in[4];
    float* loss = (float*)d_out;
    float4* partials = (float4*)d_ws;   // 256 * 16 B scratch

    yolo_loss<<<dim3(NB), dim3(1024), 0, stream>>>(
        out_t, gt_boxes, anchor, gt_classes, num_box, partials);
    reduce_partials<<<dim3(1), dim3(256), 0, stream>>>(partials, loss);
}